// Round 4
// baseline (225.459 us; speedup 1.0000x reference)
//
#include <hip/hip_runtime.h>

#define NN 50000
#define NE 800000
#define KIN 512
#define HC 128
#define SCAN_NB ((NN + 255) / 256)   // 196

typedef float f32x4 __attribute__((ext_vector_type(4)));
typedef float f32x2 __attribute__((ext_vector_type(2)));
typedef short s16x8 __attribute__((ext_vector_type(8)));

__device__ __forceinline__ ushort f2bf(float f) {
  unsigned u = __float_as_uint(f);
  unsigned r = (u + 0x7FFFu + ((u >> 16) & 1u)) >> 16;  // RNE
  return (ushort)r;
}

// JAX threefry2x32-20, partitionable path: ctr=(0,i), key=(0,42), bits=o0^o1
__device__ __forceinline__ unsigned tf_bits(unsigned i) {
  unsigned x0 = 0u, x1 = i;
  const unsigned ks0 = 0u, ks1 = 42u, ks2 = 0x1BD11BDAu ^ 42u;
  x0 += ks0; x1 += ks1;
#define R(r) { x0 += x1; x1 = (x1 << r) | (x1 >> (32 - r)); x1 ^= x0; }
  R(13) R(15) R(26) R(6)
  x0 += ks1; x1 += ks2 + 1u;
  R(17) R(29) R(16) R(24)
  x0 += ks2; x1 += ks0 + 2u;
  R(13) R(15) R(26) R(6)
  x0 += ks0; x1 += ks1 + 3u;
  R(17) R(29) R(16) R(24)
  x0 += ks1; x1 += ks2 + 4u;
  R(13) R(15) R(26) R(6)
  x0 += ks2; x1 += ks0 + 5u;
#undef R
  return x0 ^ x1;
}

// zero edge-count + W transpose/convert: Wt[c][k] bf16
__global__ void k_prep(const float* __restrict__ W, int* __restrict__ cnt,
                       ushort* __restrict__ Wt) {
  int t = blockIdx.x * 256 + threadIdx.x;   // t < 65536
  if (t < NN) cnt[t] = 0;
  if (t < KIN * HC) {
    int c = t & (HC - 1), k = t >> 7;       // W row-major [k][c]
    Wt[c * KIN + k] = f2bf(W[t]);
  }
}

__global__ void k_cnt(const int* __restrict__ ei, int* __restrict__ cnt) {
  int e = blockIdx.x * 256 + threadIdx.x;
  if (e < NE) atomicAdd(&cnt[ei[NE + e]], 1);
}

// per-block exclusive scan of cnt; off = local exclusive, bsum[b] = block total
__global__ void k_scan1(const int* __restrict__ cnt, int* __restrict__ off,
                        float* __restrict__ dinv, int* __restrict__ bsum) {
  const int i = blockIdx.x * 256 + threadIdx.x;
  const int lane = threadIdx.x & 63, wid = threadIdx.x >> 6;
  int c = (i < NN) ? cnt[i] : 0;
  if (i < NN) dinv[i] = rsqrtf((float)(c + 1));
  int v = c;
#pragma unroll
  for (int d = 1; d < 64; d <<= 1) {
    int t = __shfl_up(v, d);
    if (lane >= d) v += t;
  }
  __shared__ int wsum[4];
  if (lane == 63) wsum[wid] = v;
  __syncthreads();
  int wadd = 0;
#pragma unroll
  for (int w = 0; w < 3; w++) if (w < wid) wadd += wsum[w];
  int incl = v + wadd;
  if (i < NN) off[i] = incl - c;            // block-local exclusive
  if (threadIdx.x == 255) bsum[blockIdx.x] = incl;
}

// exclusive scan of SCAN_NB (<=256) block sums, in place
__global__ void k_scan2(int* __restrict__ bsum) {
  const int t = threadIdx.x;
  const int lane = t & 63, wid = t >> 6;
  int c = (t < SCAN_NB) ? bsum[t] : 0;
  int v = c;
#pragma unroll
  for (int d = 1; d < 64; d <<= 1) {
    int u = __shfl_up(v, d);
    if (lane >= d) v += u;
  }
  __shared__ int wsum[4];
  if (lane == 63) wsum[wid] = v;
  __syncthreads();
  int wadd = 0;
#pragma unroll
  for (int w = 0; w < 3; w++) if (w < wid) wadd += wsum[w];
  if (t < SCAN_NB) bsum[t] = v + wadd - c;  // exclusive
}

__global__ void k_scan3(int* __restrict__ off, const int* __restrict__ bsum) {
  int i = blockIdx.x * 256 + threadIdx.x;
  if (i < NN) off[i] += bsum[blockIdx.x];
  if (i == 0) off[NN] = NE;                 // total degree == NE by construction
}

// csrp[off[dst]+slot] = (bf16(dinv[src])<<16) | src   (src < 65536)
__global__ void k_fill(const int* __restrict__ ei, const int* __restrict__ off,
                       int* __restrict__ cnt, const float* __restrict__ dinv,
                       unsigned* __restrict__ csrp) {
  int e = blockIdx.x * 256 + threadIdx.x;
  if (e >= NE) return;
  int s = ei[e], d = ei[NE + e];
  int slot = atomicAdd(&cnt[d], -1) - 1;
  csrp[off[d] + slot] = ((unsigned)f2bf(dinv[s]) << 16) | (unsigned)s;
}

// x = feats @ W  (bf16 MFMA, f32 acc, bf16 out). Barrier-free: one wave owns
// 16 rows x 128 cols; A direct from global, B streams from L2-resident Wt.
__global__ void k_gemm(const float* __restrict__ feats, const ushort* __restrict__ Wt,
                       ushort* __restrict__ xb) {
  const int lane = threadIdx.x & 63;
  const int wid = threadIdx.x >> 6;
  const int r0 = (blockIdx.x * 4 + wid) * 16;
  if (r0 >= NN) return;                     // wave-uniform, no barriers in kernel

  f32x4 acc[8];
#pragma unroll
  for (int nt = 0; nt < 8; nt++) acc[nt] = f32x4{0.f, 0.f, 0.f, 0.f};

  int arow = r0 + (lane & 15); if (arow > NN - 1) arow = NN - 1;
  const float*  ap = feats + (size_t)arow * KIN + (lane >> 4) * 8;
  const ushort* bp = Wt + (lane & 15) * KIN + (lane >> 4) * 8;

#pragma unroll 4
  for (int ks = 0; ks < KIN; ks += 32) {
    f32x4 a0 = *(const f32x4*)(ap + ks);
    f32x4 a1 = *(const f32x4*)(ap + ks + 4);
    s16x8 af;
#pragma unroll
    for (int t = 0; t < 4; t++) {
      af[t]     = (short)f2bf(a0[t]);
      af[t + 4] = (short)f2bf(a1[t]);
    }
#pragma unroll
    for (int nt = 0; nt < 8; nt++) {
      const s16x8 bf = *(const s16x8*)(bp + nt * 16 * KIN + ks);
      acc[nt] = __builtin_amdgcn_mfma_f32_16x16x32_bf16(af, bf, acc[nt], 0, 0, 0);
    }
  }
  // C/D frag: col = lane&15, row = (lane>>4)*4 + j
  const int rb = r0 + (lane >> 4) * 4;
#pragma unroll
  for (int nt = 0; nt < 8; nt++) {
    int c = nt * 16 + (lane & 15);
#pragma unroll
    for (int j = 0; j < 4; j++) {
      int r = rb + j;
      if (r < NN) xb[(size_t)r * HC + c] = f2bf(acc[nt][j]);
    }
  }
}

// one wave per node: out = dropout(relu(self + sum x[src]*norm + b))
__global__ void k_agg(const ushort* __restrict__ xb, const float* __restrict__ dinv,
                      const int* __restrict__ off, const unsigned* __restrict__ csrp,
                      const float* __restrict__ b, float* __restrict__ out) {
  int n = blockIdx.x * 4 + (threadIdx.x >> 6);
  if (n >= NN) return;
  const int lane = threadIdx.x & 63;
  const int beg = off[n], end = off[n + 1];
  const float dn = dinv[n];
  f32x2 bb = *(const f32x2*)(b + lane * 2);
  unsigned sw = *(const unsigned*)(xb + (size_t)n * HC + lane * 2);
  float ax = __uint_as_float(sw << 16)         * dn * dn + bb.x;
  float ay = __uint_as_float(sw & 0xFFFF0000u) * dn * dn + bb.y;

  unsigned u = (beg < end) ? csrp[beg] : 0u;   // 1-deep csr prefetch
  for (int j = beg; j < end; j++) {
    unsigned uc = u;
    if (j + 1 < end) u = csrp[j + 1];
    int s = uc & 0xFFFFu;
    float nr = __uint_as_float(uc & 0xFFFF0000u) * dn;  // bf16(dinv[src]) * dinv[n]
    unsigned w = *(const unsigned*)(xb + (size_t)s * HC + lane * 2);
    ax += __uint_as_float(w << 16) * nr;
    ay += __uint_as_float(w & 0xFFFF0000u) * nr;
  }
  int i0 = n * HC + lane * 2;
  float vx = fmaxf(ax, 0.0f) * 2.0f;
  float vy = fmaxf(ay, 0.0f) * 2.0f;
  f32x2 r;
  r.x = (tf_bits((unsigned)i0)     >> 31) ? 0.0f : vx;
  r.y = (tf_bits((unsigned)i0 + 1) >> 31) ? 0.0f : vy;
  *(f32x2*)(out + i0) = r;
}

extern "C" void kernel_launch(void* const* d_in, const int* in_sizes, int n_in,
                              void* d_out, int out_size, void* d_ws, size_t ws_size,
                              hipStream_t stream) {
  const float* feats = (const float*)d_in[0];
  const float* W     = (const float*)d_in[1];
  const float* b     = (const float*)d_in[2];
  const int*   ei    = (const int*)d_in[3];
  float* out = (float*)d_out;

  // ws: xb[NN*HC] bf16 | Wt[HC*KIN] bf16 | dinv[NN] f32 | cnt[NN] i32 |
  //     off[NN+1] i32 | bsum[256] i32 | csrp[NE] u32   (~17 MB)
  char* ws = (char*)d_ws;
  size_t o = 0;
  ushort*   xb   = (ushort*)(ws + o);   o += ((size_t)NN * HC * 2 + 255) & ~(size_t)255;
  ushort*   Wt   = (ushort*)(ws + o);   o += ((size_t)HC * KIN * 2 + 255) & ~(size_t)255;
  float*    dinv = (float*)(ws + o);    o += ((size_t)NN * 4 + 255) & ~(size_t)255;
  int*      cnt  = (int*)(ws + o);      o += ((size_t)NN * 4 + 255) & ~(size_t)255;
  int*      off  = (int*)(ws + o);      o += ((size_t)(NN + 1) * 4 + 255) & ~(size_t)255;
  int*      bsum = (int*)(ws + o);      o += 256 * 4;
  unsigned* csrp = (unsigned*)(ws + o);

  k_prep <<<(KIN * HC + 255) / 256, 256, 0, stream>>>(W, cnt, Wt);
  k_cnt  <<<(NE + 255) / 256, 256, 0, stream>>>(ei, cnt);
  k_scan1<<<SCAN_NB, 256, 0, stream>>>(cnt, off, dinv, bsum);
  k_scan2<<<1, 256, 0, stream>>>(bsum);
  k_scan3<<<SCAN_NB, 256, 0, stream>>>(off, bsum);
  k_fill <<<(NE + 255) / 256, 256, 0, stream>>>(ei, off, cnt, dinv, csrp);
  k_gemm <<<(NN + 63) / 64, 256, 0, stream>>>(feats, Wt, xb);
  k_agg  <<<(NN + 3) / 4, 256, 0, stream>>>(xb, dinv, off, csrp, b, out);
}